// Round 5
// baseline (224.939 us; speedup 1.0000x reference)
//
#include <hip/hip_runtime.h>
#include <hip/hip_bf16.h>

#define NN 50000
#define NE 600000
#define CAP 64              // bucket capacity per node (Poisson(12): P(deg>64) ~ e^-55)

typedef __attribute__((ext_vector_type(8))) short short8v;   // 8 bf16 = 4 VGPRs
typedef __attribute__((ext_vector_type(4))) float float4v;   // MFMA C/D
typedef __attribute__((ext_vector_type(2))) float f32x2;     // packed fp32 (v_pk_fma_f32)

// Dataset facts (pinned on HW over R3-R8): floats fp32, edges int32, out fp32.
__device__ __forceinline__ float bf2f_u(unsigned short u) {
    union { unsigned int i; float f; } v; v.i = ((unsigned int)u) << 16; return v.f;
}
__device__ __forceinline__ unsigned short f2bf_u(float f) {
    __hip_bfloat16 b = __float2bfloat16(f);
    return *reinterpret_cast<unsigned short*>(&b);
}
__device__ __forceinline__ unsigned cvt_pk_bf16(float lo, float hi) {
    unsigned r;
    asm volatile("v_cvt_pk_bf16_f32 %0, %1, %2" : "=v"(r) : "v"(lo), "v"(hi));
    return r;   // D.bf16[0]=S0 (lo), D.bf16[1]=S1 (hi)
}

// ---------------------------------------------------------------------------
// prep+zero: blocks [0,128) convert fp32 W[k][n] -> bf16 Wt[n][k] (both Ws);
// blocks [128,324) zero cnt.
// ---------------------------------------------------------------------------
__global__ __launch_bounds__(256) void prep_zero(const float* __restrict__ W1,
                                                 const float* __restrict__ W2,
                                                 unsigned short* __restrict__ wt1,
                                                 unsigned short* __restrict__ wt2,
                                                 int* __restrict__ cnt) {
    int b = blockIdx.x;
    if (b < 128) {
        int t = b * 256 + threadIdx.x;             // 0..32767
        const float* src = (t < 16384) ? W1 : W2;
        unsigned short* dst = (t < 16384) ? wt1 : wt2;
        int idx = t & 16383;
        int n = idx >> 7, k = idx & 127;
        dst[idx] = f2bf_u(src[k * 128 + n]);
        return;
    }
    int g = (b - 128) * 256 + threadIdx.x;
    if (g < NN) cnt[g] = 0;
}

// ---------------------------------------------------------------------------
// GEMM body (R20 swapped-MFMA, C^T fragments): each lane owns ONE row
// (row0+wrow+(lane&15)) and 4 contiguous cols per ct (ct*16+q*4+r).
// H store: 8x uint2 (16 cvt_pk). als/ald: lane-local dot + 2-step butterfly.
// ---------------------------------------------------------------------------
template<int H, int XF32>
__device__ __forceinline__ void gemm_body(const void* __restrict__ X,
                                          const unsigned short* __restrict__ Wt,
                                          const float* __restrict__ a_src,
                                          const float* __restrict__ a_dst,
                                          unsigned short* __restrict__ Hout,
                                          float* __restrict__ als,
                                          float* __restrict__ ald, int n, int blk,
                                          unsigned short (*Xs)[136],
                                          unsigned short (*WtS)[136],
                                          float* as_s, float* ad_s) {
    const int tid = threadIdx.x;
    const int row0 = blk * 64;

    if (tid < 128) { as_s[tid] = a_src[tid]; ad_s[tid] = a_dst[tid]; }
    {   // stage pre-transposed Wt: pure uint4 copies (conflict-free)
        const uint4* Wv = (const uint4*)Wt;
#pragma unroll
        for (int i = 0; i < 8; ++i) {
            int lin = tid + 256 * i;              // 0..2047
            int r = lin >> 4, c8 = lin & 15;
            *(uint4*)&WtS[r][c8 * 8] = Wv[lin];
        }
    }
    if (XF32) {
        const float4* Xv = (const float4*)X;
#pragma unroll
        for (int i = 0; i < 8; ++i) {
            int lin = tid + 256 * i;
            int r = lin >> 5, c4 = lin & 31;
            float4 v = make_float4(0.f, 0.f, 0.f, 0.f);
            if (row0 + r < n) v = Xv[(size_t)(row0 + r) * 32 + c4];
            ushort4 o;
            o.x = f2bf_u(v.x); o.y = f2bf_u(v.y); o.z = f2bf_u(v.z); o.w = f2bf_u(v.w);
            *(ushort4*)&Xs[r][c4 * 4] = o;
        }
    } else {
        const uint4* Xv = (const uint4*)X;
#pragma unroll
        for (int i = 0; i < 4; ++i) {
            int lin = tid + 256 * i;
            int r = lin >> 4, c8 = lin & 15;
            uint4 v = make_uint4(0u, 0u, 0u, 0u);
            if (row0 + r < n) v = Xv[(size_t)(row0 + r) * 16 + c8];
            *(uint4*)&Xs[r][c8 * 8] = v;
        }
    }
    __syncthreads();

    const int lane = tid & 63;
    const int wrow = (tid >> 6) * 16;
    const int m = lane & 15, q = lane >> 4;

    float4v acc[8];
#pragma unroll
    for (int ct = 0; ct < 8; ++ct) acc[ct] = (float4v){0.f, 0.f, 0.f, 0.f};

#pragma unroll
    for (int kt = 0; kt < 4; ++kt) {
        short8v af = *(const short8v*)&Xs[wrow + m][kt * 32 + q * 8];
#pragma unroll
        for (int ct = 0; ct < 8; ++ct) {
            short8v bf = *(const short8v*)&WtS[ct * 16 + m][kt * 32 + q * 8];
            acc[ct] = __builtin_amdgcn_mfma_f32_16x16x32_bf16(bf, af, acc[ct], 0, 0, 0);
        }
    }
    // acc[ct][r] = H[row0+wrow+m][ct*16 + q*4 + r]

    const int grow = row0 + wrow + m;
    const bool ok = grow < n;

    // store H (bf16): one row per lane, 8x 8-byte stores
    if (ok) {
#pragma unroll
        for (int ct = 0; ct < 8; ++ct) {
            unsigned lo = cvt_pk_bf16(acc[ct][0], acc[ct][1]);
            unsigned hi = cvt_pk_bf16(acc[ct][2], acc[ct][3]);
            *(uint2*)&Hout[(size_t)grow * 128 + ct * 16 + q * 4] = make_uint2(lo, hi);
        }
    }

    // als/ald: lane-local partial dot over my 32 cols, butterfly over q
    if (H == 4) {
        float ps[4], pd[4];
#pragma unroll
        for (int hd = 0; hd < 4; ++hd) {
            ps[hd] = 0.f; pd[hd] = 0.f;
#pragma unroll
            for (int p2 = 0; p2 < 2; ++p2)
#pragma unroll
                for (int r = 0; r < 4; ++r) {
                    float xv = acc[2 * hd + p2][r];
                    int col = hd * 32 + p2 * 16 + q * 4 + r;
                    ps[hd] += xv * as_s[col];
                    pd[hd] += xv * ad_s[col];
                }
        }
#pragma unroll
        for (int o = 16; o < 64; o <<= 1)
#pragma unroll
            for (int hd = 0; hd < 4; ++hd) {
                ps[hd] += __shfl_xor(ps[hd], o);
                pd[hd] += __shfl_xor(pd[hd], o);
            }
        if (q == 0 && ok) {
            *(float4*)&als[(size_t)grow * 4] = make_float4(ps[0], ps[1], ps[2], ps[3]);
            *(float4*)&ald[(size_t)grow * 4] = make_float4(pd[0], pd[1], pd[2], pd[3]);
        }
    } else {
        float ps = 0.f, pd = 0.f;
#pragma unroll
        for (int ct = 0; ct < 8; ++ct)
#pragma unroll
            for (int r = 0; r < 4; ++r) {
                float xv = acc[ct][r];
                int col = ct * 16 + q * 4 + r;
                ps += xv * as_s[col];
                pd += xv * ad_s[col];
            }
#pragma unroll
        for (int o = 16; o < 64; o <<= 1) {
            ps += __shfl_xor(ps, o);
            pd += __shfl_xor(pd, o);
        }
        if (q == 0 && ok) { als[grow] = ps; ald[grow] = pd; }
    }
}

// ---------------------------------------------------------------------------
// Fused gemm (+ optional csr_fill) dispatch, R21: blocks [0,nGemm) run the
// MFMA gemm; blocks [nGemm,..) run csr_fill (atomicAdd slot + scatter). The
// two halves are independent (csr: ei/cnt; gemm: x/wt) and both feed only
// aggregate — fusing removes a serial dispatch boundary and overlaps the
// atomic-latency-bound csr work with MFMA/LDS-wait slots on shared CUs.
// (csr blocks inherit the 53KB LDS reservation -> 3 blocks/CU; 12 waves/CU
// judged sufficient for L2 atomic throughput.)
// ---------------------------------------------------------------------------
template<int H, int XF32, int CSR>
__global__ __launch_bounds__(256) void gemm_csr(const void* __restrict__ X,
                                                const unsigned short* __restrict__ Wt,
                                                const float* __restrict__ a_src,
                                                const float* __restrict__ a_dst,
                                                unsigned short* __restrict__ Hout,
                                                float* __restrict__ als,
                                                float* __restrict__ ald, int n,
                                                int nGemm,
                                                const int* __restrict__ ei,
                                                int* __restrict__ cnt,
                                                int* __restrict__ csrc) {
    __shared__ unsigned short Xs[64][136];
    __shared__ unsigned short WtS[128][136];
    __shared__ float as_s[128], ad_s[128];
    if (CSR && (int)blockIdx.x >= nGemm) {
        int e = ((int)blockIdx.x - nGemm) * 256 + threadIdx.x;
        if (e < NE) {
            int s = ei[e], d = ei[NE + e];
            s = min(max(s, 0), NN - 1);
            d = min(max(d, 0), NN - 1);
            int pos = atomicAdd(&cnt[d], 1);
            if (pos < CAP) csrc[(d << 6) + pos] = s;
        }
        return;
    }
    gemm_body<H, XF32>(X, Wt, a_src, a_dst, Hout, als, ald, n, (int)blockIdx.x,
                       Xs, WtS, as_s, ad_s);
}

// ---------------------------------------------------------------------------
// Aggregate v7 (R21): 2 nodes/wave (32 lanes each, 2 groups of 16), now
// 16 edges/round (8 per group: 2x int4 slot loads, 8 gathers in flight).
// Deg~13 nodes: 1 round (was 2) -> half the loop/exp-broadcast overhead,
// double the gather MLP. Each lane exps TWO (edge,head) logits per round
// (edges lane&3 and 4+(lane&3) of its group, own head); quad ds_swizzle
// broadcast with literal imm patterns. Tail slots: id=self + ex=0 predicate.
// FINAL=0: +bias, ELU, bf16 out. FINAL=1: +bias, fp32 out. No atomics.
// ---------------------------------------------------------------------------
template<int H, int FINAL>
__global__ __launch_bounds__(256) void aggregate(const int* __restrict__ cnt,
                                                 const int* __restrict__ csrc,
                                                 const unsigned short* __restrict__ h,
                                                 const float* __restrict__ als,
                                                 const float* __restrict__ ald,
                                                 const float* __restrict__ bias,
                                                 void* __restrict__ out) {
    const int wv = (int)((blockIdx.x * 256 + threadIdx.x) >> 6);   // wave id
    const int lane = threadIdx.x & 63;
    const int d = wv * 2 + (lane >> 5);        // 25000 waves cover 50000 nodes exactly
    const int hl = lane & 31;
    const int g2 = hl >> 4;                    // edge group within node: 0/1
    const int c0 = (hl & 15) * 8;              // this lane's 8 channels
    const int hd = (H == 4) ? (c0 >> 5) : 0;   // == (hl>>2)&3 when H==4
    const float aldd = (H == 4) ? ald[(size_t)d * 4 + hd] : ald[d];

    const char* hB   = (const char*)h;
    const char* alsB = (const char*)als;
    const char* csB  = (const char*)csrc;
    const unsigned coff = (unsigned)(c0 << 1);           // byte offset of my 8ch
    const unsigned aoff = (H == 4) ? (unsigned)(hd << 2) : 0u;
    const int myk = lane & 3;                            // my edge pair: myk, myk+4

    f32x2 acc2[4];
#pragma unroll
    for (int i = 0; i < 4; ++i) { acc2[i].x = 0.f; acc2[i].y = 0.f; }
    float den = 0.f;

    auto expw = [&](float av) {
        float v = av + aldd;
        v = fmaxf(v, 0.2f * v);        // leaky_relu, slope<1
        return __expf(fminf(v, 60.f));
    };
    auto accum = [&](uint4 hv, float ex) {
        f32x2 exv; exv.x = ex; exv.y = ex;
#pragma unroll
        for (int i = 0; i < 4; ++i) {
            unsigned w = ((const unsigned*)&hv)[i];
            f32x2 hf;
            hf.x = __uint_as_float(w << 16);
            hf.y = __uint_as_float(w & 0xffff0000u);
            acc2[i] += exv * hf;       // ch 2i (lo), 2i+1 (hi)
        }
        den += ex;
    };

    if (g2 == 0) {   // self-loop handled by group 0 of each half
        float av = (H == 4) ? als[(size_t)d * 4 + hd] : als[d];
        uint4 hv = *(const uint4*)(hB + (((unsigned)d << 8) + coff));
        accum(hv, expw(av));
    }

    const unsigned cbase = (unsigned)d << 8;             // bucket byte base
    const int c = min(cnt[d], CAP);
    for (int j0 = 0; j0 < c; j0 += 16) {
        int jb = j0 + 8 * g2;                            // my group's 8-slot base
        int4 iv0 = *(const int4*)(csB + (cbase + ((unsigned)jb << 2)));
        int4 iv1 = *(const int4*)(csB + (cbase + ((unsigned)jb << 2) + 16));
        bool p[8]; int idm[8];
#pragma unroll
        for (int k = 0; k < 4; ++k) {
            p[k] = (jb + k < c);
            idm[k] = p[k] ? ((const int*)&iv0)[k] : d;   // tail: self (valid id)
        }
#pragma unroll
        for (int k = 4; k < 8; ++k) {
            p[k] = (jb + k < c);
            idm[k] = p[k] ? ((const int*)&iv1)[k - 4] : d;
        }
        uint4 hv[8];
#pragma unroll
        for (int k = 0; k < 8; ++k)
            hv[k] = *(const uint4*)(hB + (((unsigned)idm[k] << 8) + coff));
        // two als loads + two exp chains per lane: (edge=myk, myk+4; head=hd)
        float av0 = (H == 4) ? *(const float*)(alsB + (((unsigned)idm[myk] << 4) + aoff))
                             : *(const float*)(alsB + ((unsigned)idm[myk] << 2));
        float av1 = (H == 4) ? *(const float*)(alsB + (((unsigned)idm[myk + 4] << 4) + aoff))
                             : *(const float*)(alsB + ((unsigned)idm[myk + 4] << 2));
        float em0 = expw(av0), em1 = expw(av1);
        int e0i = __float_as_int(em0), e1i = __float_as_int(em1);
        // quad broadcast (literal imm patterns — builtin needs constants)
        float ex[8];
        ex[0] = __int_as_float(__builtin_amdgcn_ds_swizzle(e0i, 0x8000));
        ex[1] = __int_as_float(__builtin_amdgcn_ds_swizzle(e0i, 0x8055));
        ex[2] = __int_as_float(__builtin_amdgcn_ds_swizzle(e0i, 0x80AA));
        ex[3] = __int_as_float(__builtin_amdgcn_ds_swizzle(e0i, 0x80FF));
        ex[4] = __int_as_float(__builtin_amdgcn_ds_swizzle(e1i, 0x8000));
        ex[5] = __int_as_float(__builtin_amdgcn_ds_swizzle(e1i, 0x8055));
        ex[6] = __int_as_float(__builtin_amdgcn_ds_swizzle(e1i, 0x80AA));
        ex[7] = __int_as_float(__builtin_amdgcn_ds_swizzle(e1i, 0x80FF));
#pragma unroll
        for (int k = 0; k < 8; ++k)
            accum(hv[k], p[k] ? ex[k] : 0.f);
    }

    // combine the 2 groups of each node: butterfly over lane 16
#pragma unroll
    for (int i = 0; i < 4; ++i) {
        acc2[i].x += __shfl_xor(acc2[i].x, 16);
        acc2[i].y += __shfl_xor(acc2[i].y, 16);
    }
    den += __shfl_xor(den, 16);
    if (g2 != 0) return;   // lanes hl<16 of each half write their node

    const float inv = 1.f / den;
    float4 b0 = *(const float4*)&bias[c0];
    float4 b1 = *(const float4*)&bias[c0 + 4];
    float v[8];
    v[0] = acc2[0].x * inv + b0.x; v[1] = acc2[0].y * inv + b0.y;
    v[2] = acc2[1].x * inv + b0.z; v[3] = acc2[1].y * inv + b0.w;
    v[4] = acc2[2].x * inv + b1.x; v[5] = acc2[2].y * inv + b1.y;
    v[6] = acc2[3].x * inv + b1.z; v[7] = acc2[3].y * inv + b1.w;
    if (FINAL) {
        float* op = (float*)out + (size_t)d * 128 + c0;
        *(float4*)op       = make_float4(v[0], v[1], v[2], v[3]);
        *(float4*)(op + 4) = make_float4(v[4], v[5], v[6], v[7]);
    } else {
#pragma unroll
        for (int i = 0; i < 8; ++i) v[i] = v[i] > 0.f ? v[i] : expm1f(v[i]);
        unsigned int pk[4];
#pragma unroll
        for (int i = 0; i < 4; ++i)
            pk[i] = (unsigned int)f2bf_u(v[2 * i]) | ((unsigned int)f2bf_u(v[2 * i + 1]) << 16);
        *(uint4*)((unsigned short*)out + (size_t)d * 128 + c0) =
            make_uint4(pk[0], pk[1], pk[2], pk[3]);
    }
}

// ---------------------------------------------------------------------------
extern "C" void kernel_launch(void* const* d_in, const int* in_sizes, int n_in,
                              void* d_out, int out_size, void* d_ws, size_t ws_size,
                              hipStream_t stream) {
    const float* x      = (const float*)d_in[0];
    const int*   ei     = (const int*)d_in[1];
    const float* W1     = (const float*)d_in[2];
    const float* a_src1 = (const float*)d_in[3];
    const float* a_dst1 = (const float*)d_in[4];
    const float* b1     = (const float*)d_in[5];
    const float* W2     = (const float*)d_in[6];
    const float* a_src2 = (const float*)d_in[7];
    const float* a_dst2 = (const float*)d_in[8];
    const float* b2     = (const float*)d_in[9];

    const int N = NN;

    // Workspace: explicit BYTE offsets, every buffer 16B-aligned.
    char* base = (char*)d_ws;
    int*   cnt  = (int*)(base + 0);                       //  50000 i
    int*   csrc = (int*)(base + 200000);                  //  50000*64 i (bucketed)
    float* als  = (float*)(base + 13000000);              // 200000 f
    float* ald  = (float*)(base + 13800000);              // 200000 f
    unsigned short* h   = (unsigned short*)(base + 14600000);  // N*128 bf16
    unsigned short* x2  = (unsigned short*)(base + 27400000);  // N*128 bf16
    unsigned short* wt1 = (unsigned short*)(base + 40200000);  // 16384 bf16
    unsigned short* wt2 = (unsigned short*)(base + 40232768);  // 16384 bf16
    // total ~40.27 MB

    const int gemmGrid  = (N + 63) / 64;          // 782
    const int edgeGrid  = (NE + 255) / 256;       // 2344
    const int zeroGrid  = (N + 255) / 256;        // 196
    const int aggGrid   = N / 8;                  // 6250 (2 nodes/wave, 4 waves/block)

    prep_zero<<<128 + zeroGrid, 256, 0, stream>>>(W1, W2, wt1, wt2, cnt);
    // fused: gemm layer-1 (blocks [0,782)) + csr_fill (blocks [782,3126))
    gemm_csr<4, 1, 1><<<gemmGrid + edgeGrid, 256, 0, stream>>>(
        x, wt1, a_src1, a_dst1, h, als, ald, N, gemmGrid, ei, cnt, csrc);
    aggregate<4, 0><<<aggGrid, 256, 0, stream>>>(cnt, csrc, h, als, ald, b1, x2);
    gemm_csr<1, 0, 0><<<gemmGrid, 256, 0, stream>>>(
        x2, wt2, a_src2, a_dst2, h, als, ald, N, gemmGrid, ei, cnt, csrc);
    aggregate<1, 1><<<aggGrid, 256, 0, stream>>>(cnt, csrc, h, als, ald, b2, d_out);
}

// Round 6
// 218.785 us; speedup vs baseline: 1.0281x; 1.0281x over previous
//
#include <hip/hip_runtime.h>
#include <hip/hip_bf16.h>

#define NN 50000
#define NE 600000
#define CAP 64              // bucket capacity per node (Poisson(12): P(deg>64) ~ e^-55)

typedef __attribute__((ext_vector_type(8))) short short8v;   // 8 bf16 = 4 VGPRs
typedef __attribute__((ext_vector_type(4))) float float4v;   // MFMA C/D
typedef __attribute__((ext_vector_type(2))) float f32x2;     // packed fp32 (v_pk_fma_f32)

// Dataset facts (pinned on HW over R3-R8): floats fp32, edges int32, out fp32.
__device__ __forceinline__ float bf2f_u(unsigned short u) {
    union { unsigned int i; float f; } v; v.i = ((unsigned int)u) << 16; return v.f;
}
__device__ __forceinline__ unsigned short f2bf_u(float f) {
    __hip_bfloat16 b = __float2bfloat16(f);
    return *reinterpret_cast<unsigned short*>(&b);
}
__device__ __forceinline__ unsigned cvt_pk_bf16(float lo, float hi) {
    unsigned r;
    asm volatile("v_cvt_pk_bf16_f32 %0, %1, %2" : "=v"(r) : "v"(lo), "v"(hi));
    return r;   // D.bf16[0]=S0 (lo), D.bf16[1]=S1 (hi)
}

// ---------------------------------------------------------------------------
// prep+zero: blocks [0,128) convert fp32 W[k][n] -> bf16 Wt[n][k] (both Ws);
// blocks [128,324) zero cnt.
// ---------------------------------------------------------------------------
__global__ __launch_bounds__(256) void prep_zero(const float* __restrict__ W1,
                                                 const float* __restrict__ W2,
                                                 unsigned short* __restrict__ wt1,
                                                 unsigned short* __restrict__ wt2,
                                                 int* __restrict__ cnt) {
    int b = blockIdx.x;
    if (b < 128) {
        int t = b * 256 + threadIdx.x;             // 0..32767
        const float* src = (t < 16384) ? W1 : W2;
        unsigned short* dst = (t < 16384) ? wt1 : wt2;
        int idx = t & 16383;
        int n = idx >> 7, k = idx & 127;
        dst[idx] = f2bf_u(src[k * 128 + n]);
        return;
    }
    int g = (b - 128) * 256 + threadIdx.x;
    if (g < NN) cnt[g] = 0;
}

// ---------------------------------------------------------------------------
// Bucketed CSR fill — STANDALONE again (R22). R5's fusion into the gemm
// dispatch made these 2344 blocks inherit the 53KB LDS reservation ->
// 3 blocks/CU (12 waves) for pure atomic-latency work that needs occupancy:
// gemm_csr ran 70us @ 2.9% VALUBusy / 24% occupancy. 0-LDS standalone runs
// at 32 waves/CU. LESSON: never fuse a latency-bound role into a high-LDS
// kernel — LDS allocation is per-kernel, occupancy is shared.
// ---------------------------------------------------------------------------
__global__ __launch_bounds__(256) void csr_fill(const int* __restrict__ ei,
                                                int* __restrict__ cnt,
                                                int* __restrict__ csrc) {
    int e = blockIdx.x * 256 + threadIdx.x;
    if (e >= NE) return;
    int s = ei[e], d = ei[NE + e];
    s = min(max(s, 0), NN - 1);
    d = min(max(d, 0), NN - 1);
    int pos = atomicAdd(&cnt[d], 1);
    if (pos < CAP) csrc[(d << 6) + pos] = s;
}

// ---------------------------------------------------------------------------
// MFMA bf16 GEMM (R20 swapped-MFMA, C^T fragments): each lane owns ONE row
// (row0+wrow+(lane&15)) and 4 contiguous cols per ct (ct*16+q*4+r).
// H store: 8x uint2 (16 cvt_pk). als/ald: lane-local dot + 2-step butterfly.
// ---------------------------------------------------------------------------
template<int H, int XF32>
__global__ __launch_bounds__(256) void gemm_fused(const void* __restrict__ X,
                                                  const unsigned short* __restrict__ Wt,
                                                  const float* __restrict__ a_src,
                                                  const float* __restrict__ a_dst,
                                                  unsigned short* __restrict__ Hout,
                                                  float* __restrict__ als,
                                                  float* __restrict__ ald, int n) {
    __shared__ unsigned short Xs[64][136];
    __shared__ unsigned short WtS[128][136];
    __shared__ float as_s[128], ad_s[128];
    const int tid = threadIdx.x;
    const int row0 = blockIdx.x * 64;

    if (tid < 128) { as_s[tid] = a_src[tid]; ad_s[tid] = a_dst[tid]; }
    {   // stage pre-transposed Wt: pure uint4 copies (conflict-free)
        const uint4* Wv = (const uint4*)Wt;
#pragma unroll
        for (int i = 0; i < 8; ++i) {
            int lin = tid + 256 * i;              // 0..2047
            int r = lin >> 4, c8 = lin & 15;
            *(uint4*)&WtS[r][c8 * 8] = Wv[lin];
        }
    }
    if (XF32) {
        const float4* Xv = (const float4*)X;
#pragma unroll
        for (int i = 0; i < 8; ++i) {
            int lin = tid + 256 * i;
            int r = lin >> 5, c4 = lin & 31;
            float4 v = make_float4(0.f, 0.f, 0.f, 0.f);
            if (row0 + r < n) v = Xv[(size_t)(row0 + r) * 32 + c4];
            ushort4 o;
            o.x = f2bf_u(v.x); o.y = f2bf_u(v.y); o.z = f2bf_u(v.z); o.w = f2bf_u(v.w);
            *(ushort4*)&Xs[r][c4 * 4] = o;
        }
    } else {
        const uint4* Xv = (const uint4*)X;
#pragma unroll
        for (int i = 0; i < 4; ++i) {
            int lin = tid + 256 * i;
            int r = lin >> 4, c8 = lin & 15;
            uint4 v = make_uint4(0u, 0u, 0u, 0u);
            if (row0 + r < n) v = Xv[(size_t)(row0 + r) * 16 + c8];
            *(uint4*)&Xs[r][c8 * 8] = v;
        }
    }
    __syncthreads();

    const int lane = tid & 63;
    const int wrow = (tid >> 6) * 16;
    const int m = lane & 15, q = lane >> 4;

    float4v acc[8];
#pragma unroll
    for (int ct = 0; ct < 8; ++ct) acc[ct] = (float4v){0.f, 0.f, 0.f, 0.f};

#pragma unroll
    for (int kt = 0; kt < 4; ++kt) {
        short8v af = *(const short8v*)&Xs[wrow + m][kt * 32 + q * 8];
#pragma unroll
        for (int ct = 0; ct < 8; ++ct) {
            short8v bf = *(const short8v*)&WtS[ct * 16 + m][kt * 32 + q * 8];
            acc[ct] = __builtin_amdgcn_mfma_f32_16x16x32_bf16(bf, af, acc[ct], 0, 0, 0);
        }
    }
    // acc[ct][r] = H[row0+wrow+m][ct*16 + q*4 + r]

    const int grow = row0 + wrow + m;
    const bool ok = grow < n;

    // store H (bf16): one row per lane, 8x 8-byte stores
    if (ok) {
#pragma unroll
        for (int ct = 0; ct < 8; ++ct) {
            unsigned lo = cvt_pk_bf16(acc[ct][0], acc[ct][1]);
            unsigned hi = cvt_pk_bf16(acc[ct][2], acc[ct][3]);
            *(uint2*)&Hout[(size_t)grow * 128 + ct * 16 + q * 4] = make_uint2(lo, hi);
        }
    }

    // als/ald: lane-local partial dot over my 32 cols, butterfly over q
    if (H == 4) {
        float ps[4], pd[4];
#pragma unroll
        for (int hd = 0; hd < 4; ++hd) {
            ps[hd] = 0.f; pd[hd] = 0.f;
#pragma unroll
            for (int p2 = 0; p2 < 2; ++p2)
#pragma unroll
                for (int r = 0; r < 4; ++r) {
                    float xv = acc[2 * hd + p2][r];
                    int col = hd * 32 + p2 * 16 + q * 4 + r;
                    ps[hd] += xv * as_s[col];
                    pd[hd] += xv * ad_s[col];
                }
        }
#pragma unroll
        for (int o = 16; o < 64; o <<= 1)
#pragma unroll
            for (int hd = 0; hd < 4; ++hd) {
                ps[hd] += __shfl_xor(ps[hd], o);
                pd[hd] += __shfl_xor(pd[hd], o);
            }
        if (q == 0 && ok) {
            *(float4*)&als[(size_t)grow * 4] = make_float4(ps[0], ps[1], ps[2], ps[3]);
            *(float4*)&ald[(size_t)grow * 4] = make_float4(pd[0], pd[1], pd[2], pd[3]);
        }
    } else {
        float ps = 0.f, pd = 0.f;
#pragma unroll
        for (int ct = 0; ct < 8; ++ct)
#pragma unroll
            for (int r = 0; r < 4; ++r) {
                float xv = acc[ct][r];
                int col = ct * 16 + q * 4 + r;
                ps += xv * as_s[col];
                pd += xv * ad_s[col];
            }
#pragma unroll
        for (int o = 16; o < 64; o <<= 1) {
            ps += __shfl_xor(ps, o);
            pd += __shfl_xor(pd, o);
        }
        if (q == 0 && ok) { als[grow] = ps; ald[grow] = pd; }
    }
}

// ---------------------------------------------------------------------------
// Aggregate v7 (kept from R21): 2 nodes/wave (32 lanes each, 2 groups of 16),
// 16 edges/round (8 per group: 2x int4 slot loads, 8 gathers in flight).
// Deg~13 nodes: 1 round -> half the loop/exp-broadcast overhead, double the
// gather MLP. Each lane exps TWO (edge,head) logits per round; quad
// ds_swizzle broadcast with literal imm patterns. Tail: id=self + ex=0.
// FINAL=0: +bias, ELU, bf16 out. FINAL=1: +bias, fp32 out. No atomics.
// ---------------------------------------------------------------------------
template<int H, int FINAL>
__global__ __launch_bounds__(256) void aggregate(const int* __restrict__ cnt,
                                                 const int* __restrict__ csrc,
                                                 const unsigned short* __restrict__ h,
                                                 const float* __restrict__ als,
                                                 const float* __restrict__ ald,
                                                 const float* __restrict__ bias,
                                                 void* __restrict__ out) {
    const int wv = (int)((blockIdx.x * 256 + threadIdx.x) >> 6);   // wave id
    const int lane = threadIdx.x & 63;
    const int d = wv * 2 + (lane >> 5);        // 25000 waves cover 50000 nodes exactly
    const int hl = lane & 31;
    const int g2 = hl >> 4;                    // edge group within node: 0/1
    const int c0 = (hl & 15) * 8;              // this lane's 8 channels
    const int hd = (H == 4) ? (c0 >> 5) : 0;   // == (hl>>2)&3 when H==4
    const float aldd = (H == 4) ? ald[(size_t)d * 4 + hd] : ald[d];

    const char* hB   = (const char*)h;
    const char* alsB = (const char*)als;
    const char* csB  = (const char*)csrc;
    const unsigned coff = (unsigned)(c0 << 1);           // byte offset of my 8ch
    const unsigned aoff = (H == 4) ? (unsigned)(hd << 2) : 0u;
    const int myk = lane & 3;                            // my edge pair: myk, myk+4

    f32x2 acc2[4];
#pragma unroll
    for (int i = 0; i < 4; ++i) { acc2[i].x = 0.f; acc2[i].y = 0.f; }
    float den = 0.f;

    auto expw = [&](float av) {
        float v = av + aldd;
        v = fmaxf(v, 0.2f * v);        // leaky_relu, slope<1
        return __expf(fminf(v, 60.f));
    };
    auto accum = [&](uint4 hv, float ex) {
        f32x2 exv; exv.x = ex; exv.y = ex;
#pragma unroll
        for (int i = 0; i < 4; ++i) {
            unsigned w = ((const unsigned*)&hv)[i];
            f32x2 hf;
            hf.x = __uint_as_float(w << 16);
            hf.y = __uint_as_float(w & 0xffff0000u);
            acc2[i] += exv * hf;       // ch 2i (lo), 2i+1 (hi)
        }
        den += ex;
    };

    if (g2 == 0) {   // self-loop handled by group 0 of each half
        float av = (H == 4) ? als[(size_t)d * 4 + hd] : als[d];
        uint4 hv = *(const uint4*)(hB + (((unsigned)d << 8) + coff));
        accum(hv, expw(av));
    }

    const unsigned cbase = (unsigned)d << 8;             // bucket byte base
    const int c = min(cnt[d], CAP);
    for (int j0 = 0; j0 < c; j0 += 16) {
        int jb = j0 + 8 * g2;                            // my group's 8-slot base
        int4 iv0 = *(const int4*)(csB + (cbase + ((unsigned)jb << 2)));
        int4 iv1 = *(const int4*)(csB + (cbase + ((unsigned)jb << 2) + 16));
        bool p[8]; int idm[8];
#pragma unroll
        for (int k = 0; k < 4; ++k) {
            p[k] = (jb + k < c);
            idm[k] = p[k] ? ((const int*)&iv0)[k] : d;   // tail: self (valid id)
        }
#pragma unroll
        for (int k = 4; k < 8; ++k) {
            p[k] = (jb + k < c);
            idm[k] = p[k] ? ((const int*)&iv1)[k - 4] : d;
        }
        uint4 hv[8];
#pragma unroll
        for (int k = 0; k < 8; ++k)
            hv[k] = *(const uint4*)(hB + (((unsigned)idm[k] << 8) + coff));
        // two als loads + two exp chains per lane: (edge=myk, myk+4; head=hd)
        float av0 = (H == 4) ? *(const float*)(alsB + (((unsigned)idm[myk] << 4) + aoff))
                             : *(const float*)(alsB + ((unsigned)idm[myk] << 2));
        float av1 = (H == 4) ? *(const float*)(alsB + (((unsigned)idm[myk + 4] << 4) + aoff))
                             : *(const float*)(alsB + ((unsigned)idm[myk + 4] << 2));
        float em0 = expw(av0), em1 = expw(av1);
        int e0i = __float_as_int(em0), e1i = __float_as_int(em1);
        // quad broadcast (literal imm patterns — builtin needs constants)
        float ex[8];
        ex[0] = __int_as_float(__builtin_amdgcn_ds_swizzle(e0i, 0x8000));
        ex[1] = __int_as_float(__builtin_amdgcn_ds_swizzle(e0i, 0x8055));
        ex[2] = __int_as_float(__builtin_amdgcn_ds_swizzle(e0i, 0x80AA));
        ex[3] = __int_as_float(__builtin_amdgcn_ds_swizzle(e0i, 0x80FF));
        ex[4] = __int_as_float(__builtin_amdgcn_ds_swizzle(e1i, 0x8000));
        ex[5] = __int_as_float(__builtin_amdgcn_ds_swizzle(e1i, 0x8055));
        ex[6] = __int_as_float(__builtin_amdgcn_ds_swizzle(e1i, 0x80AA));
        ex[7] = __int_as_float(__builtin_amdgcn_ds_swizzle(e1i, 0x80FF));
#pragma unroll
        for (int k = 0; k < 8; ++k)
            accum(hv[k], p[k] ? ex[k] : 0.f);
    }

    // combine the 2 groups of each node: butterfly over lane 16
#pragma unroll
    for (int i = 0; i < 4; ++i) {
        acc2[i].x += __shfl_xor(acc2[i].x, 16);
        acc2[i].y += __shfl_xor(acc2[i].y, 16);
    }
    den += __shfl_xor(den, 16);
    if (g2 != 0) return;   // lanes hl<16 of each half write their node

    const float inv = 1.f / den;
    float4 b0 = *(const float4*)&bias[c0];
    float4 b1 = *(const float4*)&bias[c0 + 4];
    float v[8];
    v[0] = acc2[0].x * inv + b0.x; v[1] = acc2[0].y * inv + b0.y;
    v[2] = acc2[1].x * inv + b0.z; v[3] = acc2[1].y * inv + b0.w;
    v[4] = acc2[2].x * inv + b1.x; v[5] = acc2[2].y * inv + b1.y;
    v[6] = acc2[3].x * inv + b1.z; v[7] = acc2[3].y * inv + b1.w;
    if (FINAL) {
        float* op = (float*)out + (size_t)d * 128 + c0;
        *(float4*)op       = make_float4(v[0], v[1], v[2], v[3]);
        *(float4*)(op + 4) = make_float4(v[4], v[5], v[6], v[7]);
    } else {
#pragma unroll
        for (int i = 0; i < 8; ++i) v[i] = v[i] > 0.f ? v[i] : expm1f(v[i]);
        unsigned int pk[4];
#pragma unroll
        for (int i = 0; i < 4; ++i)
            pk[i] = (unsigned int)f2bf_u(v[2 * i]) | ((unsigned int)f2bf_u(v[2 * i + 1]) << 16);
        *(uint4*)((unsigned short*)out + (size_t)d * 128 + c0) =
            make_uint4(pk[0], pk[1], pk[2], pk[3]);
    }
}

// ---------------------------------------------------------------------------
extern "C" void kernel_launch(void* const* d_in, const int* in_sizes, int n_in,
                              void* d_out, int out_size, void* d_ws, size_t ws_size,
                              hipStream_t stream) {
    const float* x      = (const float*)d_in[0];
    const int*   ei     = (const int*)d_in[1];
    const float* W1     = (const float*)d_in[2];
    const float* a_src1 = (const float*)d_in[3];
    const float* a_dst1 = (const float*)d_in[4];
    const float* b1     = (const float*)d_in[5];
    const float* W2     = (const float*)d_in[6];
    const float* a_src2 = (const float*)d_in[7];
    const float* a_dst2 = (const float*)d_in[8];
    const float* b2     = (const float*)d_in[9];

    const int N = NN;

    // Workspace: explicit BYTE offsets, every buffer 16B-aligned.
    char* base = (char*)d_ws;
    int*   cnt  = (int*)(base + 0);                       //  50000 i
    int*   csrc = (int*)(base + 200000);                  //  50000*64 i (bucketed)
    float* als  = (float*)(base + 13000000);              // 200000 f
    float* ald  = (float*)(base + 13800000);              // 200000 f
    unsigned short* h   = (unsigned short*)(base + 14600000);  // N*128 bf16
    unsigned short* x2  = (unsigned short*)(base + 27400000);  // N*128 bf16
    unsigned short* wt1 = (unsigned short*)(base + 40200000);  // 16384 bf16
    unsigned short* wt2 = (unsigned short*)(base + 40232768);  // 16384 bf16
    // total ~40.27 MB

    const int gemmGrid  = (N + 63) / 64;          // 782
    const int edgeGrid  = (NE + 255) / 256;       // 2344
    const int zeroGrid  = (N + 255) / 256;        // 196
    const int aggGrid   = N / 8;                  // 6250 (2 nodes/wave, 4 waves/block)

    prep_zero<<<128 + zeroGrid, 256, 0, stream>>>(W1, W2, wt1, wt2, cnt);
    csr_fill<<<edgeGrid, 256, 0, stream>>>(ei, cnt, csrc);
    gemm_fused<4, 1><<<gemmGrid, 256, 0, stream>>>(x, wt1, a_src1, a_dst1, h, als, ald, N);
    aggregate<4, 0><<<aggGrid, 256, 0, stream>>>(cnt, csrc, h, als, ald, b1, x2);
    gemm_fused<1, 0><<<gemmGrid, 256, 0, stream>>>(x2, wt2, a_src2, a_dst2, h, als, ald, N);
    aggregate<1, 1><<<aggGrid, 256, 0, stream>>>(cnt, csrc, h, als, ald, b2, d_out);
}

// Round 7
// 215.414 us; speedup vs baseline: 1.0442x; 1.0156x over previous
//
#include <hip/hip_runtime.h>
#include <hip/hip_bf16.h>

#define NN 50000
#define NE 600000
#define CAP 64              // bucket capacity per node (Poisson(12): P(deg>64) ~ e^-55)

typedef __attribute__((ext_vector_type(8))) short short8v;   // 8 bf16 = 4 VGPRs
typedef __attribute__((ext_vector_type(4))) float float4v;   // MFMA C/D
typedef __attribute__((ext_vector_type(2))) float f32x2;     // packed fp32 (v_pk_fma_f32)

// Dataset facts (pinned on HW over R3-R8): floats fp32, edges int32, out fp32.
__device__ __forceinline__ float bf2f_u(unsigned short u) {
    union { unsigned int i; float f; } v; v.i = ((unsigned int)u) << 16; return v.f;
}
__device__ __forceinline__ unsigned short f2bf_u(float f) {
    __hip_bfloat16 b = __float2bfloat16(f);
    return *reinterpret_cast<unsigned short*>(&b);
}
__device__ __forceinline__ unsigned cvt_pk_bf16(float lo, float hi) {
    unsigned r;
    asm volatile("v_cvt_pk_bf16_f32 %0, %1, %2" : "=v"(r) : "v"(lo), "v"(hi));
    return r;   // D.bf16[0]=S0 (lo), D.bf16[1]=S1 (hi)
}

// ---------------------------------------------------------------------------
// prep+zero: blocks [0,128) convert fp32 W[k][n] -> bf16 Wt[n][k] (both Ws);
// blocks [128,324) zero cnt.
// ---------------------------------------------------------------------------
__global__ __launch_bounds__(256) void prep_zero(const float* __restrict__ W1,
                                                 const float* __restrict__ W2,
                                                 unsigned short* __restrict__ wt1,
                                                 unsigned short* __restrict__ wt2,
                                                 int* __restrict__ cnt) {
    int b = blockIdx.x;
    if (b < 128) {
        int t = b * 256 + threadIdx.x;             // 0..32767
        const float* src = (t < 16384) ? W1 : W2;
        unsigned short* dst = (t < 16384) ? wt1 : wt2;
        int idx = t & 16383;
        int n = idx >> 7, k = idx & 127;
        dst[idx] = f2bf_u(src[k * 128 + n]);
        return;
    }
    int g = (b - 128) * 256 + threadIdx.x;
    if (g < NN) cnt[g] = 0;
}

// ---------------------------------------------------------------------------
// Bucketed CSR fill — standalone 0-LDS (R22 lesson: never fuse a
// latency-bound role into a high-LDS kernel; LDS allocation is per-kernel).
// ---------------------------------------------------------------------------
__global__ __launch_bounds__(256) void csr_fill(const int* __restrict__ ei,
                                                int* __restrict__ cnt,
                                                int* __restrict__ csrc) {
    int e = blockIdx.x * 256 + threadIdx.x;
    if (e >= NE) return;
    int s = ei[e], d = ei[NE + e];
    s = min(max(s, 0), NN - 1);
    d = min(max(d, 0), NN - 1);
    int pos = atomicAdd(&cnt[d], 1);
    if (pos < CAP) csrc[(d << 6) + pos] = s;
}

// ---------------------------------------------------------------------------
// MFMA bf16 GEMM, R23: Xs LDS tile DELETED. In the swapped-MFMA (C^T) layout
// each lane's A-side fragment af[kt] is 8 contiguous bf16 of its OWN output
// row -> plain per-lane global load (layer2: 16B; layer1: 2x float4 + 4
// cvt_pk), issued BEFORE the barrier so HBM latency hides under Wt staging.
// Removes 8 staged loads + 8 LDS writes + 16 ds_read per thread; LDS
// 53248 -> 35840 -> 4 blocks/CU (was 3), deepening the block pipeline.
// Correctness: lane m's acc depends only on X-row grow (its own MFMA
// column), so clamped OOB rows pollute only discarded lanes.
// ---------------------------------------------------------------------------
template<int H, int XF32>
__global__ __launch_bounds__(256) void gemm_fused(const void* __restrict__ X,
                                                  const unsigned short* __restrict__ Wt,
                                                  const float* __restrict__ a_src,
                                                  const float* __restrict__ a_dst,
                                                  unsigned short* __restrict__ Hout,
                                                  float* __restrict__ als,
                                                  float* __restrict__ ald, int n) {
    __shared__ unsigned short WtS[128][136];
    __shared__ float as_s[128], ad_s[128];
    const int tid = threadIdx.x;
    const int row0 = blockIdx.x * 64;

    if (tid < 128) { as_s[tid] = a_src[tid]; ad_s[tid] = a_dst[tid]; }
    {   // stage pre-transposed Wt: pure uint4 copies (conflict-free)
        const uint4* Wv = (const uint4*)Wt;
#pragma unroll
        for (int i = 0; i < 8; ++i) {
            int lin = tid + 256 * i;              // 0..2047
            int r = lin >> 4, c8 = lin & 15;
            *(uint4*)&WtS[r][c8 * 8] = Wv[lin];
        }
    }

    const int lane = tid & 63;
    const int wrow = (tid >> 6) * 16;
    const int m = lane & 15, q = lane >> 4;
    const int grow = row0 + wrow + m;
    const bool ok = grow < n;
    const int arow = min(grow, n - 1);            // clamp: OOB lanes discarded

    // af direct load (global -> reg), overlaps Wt staging latency
    short8v af[4];
    if (XF32) {
        const float4* Xv = (const float4*)X;      // row stride = 32 float4
#pragma unroll
        for (int kt = 0; kt < 4; ++kt) {
            float4 a0 = Xv[(size_t)arow * 32 + kt * 8 + q * 2];
            float4 a1 = Xv[(size_t)arow * 32 + kt * 8 + q * 2 + 1];
            uint4 u = make_uint4(cvt_pk_bf16(a0.x, a0.y), cvt_pk_bf16(a0.z, a0.w),
                                 cvt_pk_bf16(a1.x, a1.y), cvt_pk_bf16(a1.z, a1.w));
            af[kt] = *(short8v*)&u;
        }
    } else {
        const unsigned short* Xb = (const unsigned short*)X;
#pragma unroll
        for (int kt = 0; kt < 4; ++kt)
            af[kt] = *(const short8v*)&Xb[(size_t)arow * 128 + kt * 32 + q * 8];
    }
    __syncthreads();   // WtS ready

    float4v acc[8];
#pragma unroll
    for (int ct = 0; ct < 8; ++ct) acc[ct] = (float4v){0.f, 0.f, 0.f, 0.f};

#pragma unroll
    for (int kt = 0; kt < 4; ++kt) {
#pragma unroll
        for (int ct = 0; ct < 8; ++ct) {
            short8v bf = *(const short8v*)&WtS[ct * 16 + m][kt * 32 + q * 8];
            acc[ct] = __builtin_amdgcn_mfma_f32_16x16x32_bf16(bf, af[kt], acc[ct], 0, 0, 0);
        }
    }
    // acc[ct][r] = H[grow][ct*16 + q*4 + r]

    // store H (bf16): one row per lane, 8x 8-byte stores
    if (ok) {
#pragma unroll
        for (int ct = 0; ct < 8; ++ct) {
            unsigned lo = cvt_pk_bf16(acc[ct][0], acc[ct][1]);
            unsigned hi = cvt_pk_bf16(acc[ct][2], acc[ct][3]);
            *(uint2*)&Hout[(size_t)grow * 128 + ct * 16 + q * 4] = make_uint2(lo, hi);
        }
    }

    // als/ald: lane-local partial dot over my 32 cols, butterfly over q
    if (H == 4) {
        float ps[4], pd[4];
#pragma unroll
        for (int hd = 0; hd < 4; ++hd) {
            ps[hd] = 0.f; pd[hd] = 0.f;
#pragma unroll
            for (int p2 = 0; p2 < 2; ++p2)
#pragma unroll
                for (int r = 0; r < 4; ++r) {
                    float xv = acc[2 * hd + p2][r];
                    int col = hd * 32 + p2 * 16 + q * 4 + r;
                    ps[hd] += xv * as_s[col];
                    pd[hd] += xv * ad_s[col];
                }
        }
#pragma unroll
        for (int o = 16; o < 64; o <<= 1)
#pragma unroll
            for (int hd = 0; hd < 4; ++hd) {
                ps[hd] += __shfl_xor(ps[hd], o);
                pd[hd] += __shfl_xor(pd[hd], o);
            }
        if (q == 0 && ok) {
            *(float4*)&als[(size_t)grow * 4] = make_float4(ps[0], ps[1], ps[2], ps[3]);
            *(float4*)&ald[(size_t)grow * 4] = make_float4(pd[0], pd[1], pd[2], pd[3]);
        }
    } else {
        float ps = 0.f, pd = 0.f;
#pragma unroll
        for (int ct = 0; ct < 8; ++ct)
#pragma unroll
            for (int r = 0; r < 4; ++r) {
                float xv = acc[ct][r];
                int col = ct * 16 + q * 4 + r;
                ps += xv * as_s[col];
                pd += xv * ad_s[col];
            }
#pragma unroll
        for (int o = 16; o < 64; o <<= 1) {
            ps += __shfl_xor(ps, o);
            pd += __shfl_xor(pd, o);
        }
        if (q == 0 && ok) { als[grow] = ps; ald[grow] = pd; }
    }
}

// ---------------------------------------------------------------------------
// Aggregate v7 (unchanged; R6 showed v7 == v6: occupancy x in-flight-gathers
// product is VGPR-invariant — aggregate is memory-parallelism-bound near its
// ~16.5us compulsory-fetch floor x ~1.7).
// ---------------------------------------------------------------------------
template<int H, int FINAL>
__global__ __launch_bounds__(256) void aggregate(const int* __restrict__ cnt,
                                                 const int* __restrict__ csrc,
                                                 const unsigned short* __restrict__ h,
                                                 const float* __restrict__ als,
                                                 const float* __restrict__ ald,
                                                 const float* __restrict__ bias,
                                                 void* __restrict__ out) {
    const int wv = (int)((blockIdx.x * 256 + threadIdx.x) >> 6);   // wave id
    const int lane = threadIdx.x & 63;
    const int d = wv * 2 + (lane >> 5);        // 25000 waves cover 50000 nodes exactly
    const int hl = lane & 31;
    const int g2 = hl >> 4;                    // edge group within node: 0/1
    const int c0 = (hl & 15) * 8;              // this lane's 8 channels
    const int hd = (H == 4) ? (c0 >> 5) : 0;   // == (hl>>2)&3 when H==4
    const float aldd = (H == 4) ? ald[(size_t)d * 4 + hd] : ald[d];

    const char* hB   = (const char*)h;
    const char* alsB = (const char*)als;
    const char* csB  = (const char*)csrc;
    const unsigned coff = (unsigned)(c0 << 1);           // byte offset of my 8ch
    const unsigned aoff = (H == 4) ? (unsigned)(hd << 2) : 0u;
    const int myk = lane & 3;                            // my edge pair: myk, myk+4

    f32x2 acc2[4];
#pragma unroll
    for (int i = 0; i < 4; ++i) { acc2[i].x = 0.f; acc2[i].y = 0.f; }
    float den = 0.f;

    auto expw = [&](float av) {
        float v = av + aldd;
        v = fmaxf(v, 0.2f * v);        // leaky_relu, slope<1
        return __expf(fminf(v, 60.f));
    };
    auto accum = [&](uint4 hv, float ex) {
        f32x2 exv; exv.x = ex; exv.y = ex;
#pragma unroll
        for (int i = 0; i < 4; ++i) {
            unsigned w = ((const unsigned*)&hv)[i];
            f32x2 hf;
            hf.x = __uint_as_float(w << 16);
            hf.y = __uint_as_float(w & 0xffff0000u);
            acc2[i] += exv * hf;       // ch 2i (lo), 2i+1 (hi)
        }
        den += ex;
    };

    if (g2 == 0) {   // self-loop handled by group 0 of each half
        float av = (H == 4) ? als[(size_t)d * 4 + hd] : als[d];
        uint4 hv = *(const uint4*)(hB + (((unsigned)d << 8) + coff));
        accum(hv, expw(av));
    }

    const unsigned cbase = (unsigned)d << 8;             // bucket byte base
    const int c = min(cnt[d], CAP);
    for (int j0 = 0; j0 < c; j0 += 16) {
        int jb = j0 + 8 * g2;                            // my group's 8-slot base
        int4 iv0 = *(const int4*)(csB + (cbase + ((unsigned)jb << 2)));
        int4 iv1 = *(const int4*)(csB + (cbase + ((unsigned)jb << 2) + 16));
        bool p[8]; int idm[8];
#pragma unroll
        for (int k = 0; k < 4; ++k) {
            p[k] = (jb + k < c);
            idm[k] = p[k] ? ((const int*)&iv0)[k] : d;   // tail: self (valid id)
        }
#pragma unroll
        for (int k = 4; k < 8; ++k) {
            p[k] = (jb + k < c);
            idm[k] = p[k] ? ((const int*)&iv1)[k - 4] : d;
        }
        uint4 hv[8];
#pragma unroll
        for (int k = 0; k < 8; ++k)
            hv[k] = *(const uint4*)(hB + (((unsigned)idm[k] << 8) + coff));
        // two als loads + two exp chains per lane: (edge=myk, myk+4; head=hd)
        float av0 = (H == 4) ? *(const float*)(alsB + (((unsigned)idm[myk] << 4) + aoff))
                             : *(const float*)(alsB + ((unsigned)idm[myk] << 2));
        float av1 = (H == 4) ? *(const float*)(alsB + (((unsigned)idm[myk + 4] << 4) + aoff))
                             : *(const float*)(alsB + ((unsigned)idm[myk + 4] << 2));
        float em0 = expw(av0), em1 = expw(av1);
        int e0i = __float_as_int(em0), e1i = __float_as_int(em1);
        // quad broadcast (literal imm patterns — builtin needs constants)
        float ex[8];
        ex[0] = __int_as_float(__builtin_amdgcn_ds_swizzle(e0i, 0x8000));
        ex[1] = __int_as_float(__builtin_amdgcn_ds_swizzle(e0i, 0x8055));
        ex[2] = __int_as_float(__builtin_amdgcn_ds_swizzle(e0i, 0x80AA));
        ex[3] = __int_as_float(__builtin_amdgcn_ds_swizzle(e0i, 0x80FF));
        ex[4] = __int_as_float(__builtin_amdgcn_ds_swizzle(e1i, 0x8000));
        ex[5] = __int_as_float(__builtin_amdgcn_ds_swizzle(e1i, 0x8055));
        ex[6] = __int_as_float(__builtin_amdgcn_ds_swizzle(e1i, 0x80AA));
        ex[7] = __int_as_float(__builtin_amdgcn_ds_swizzle(e1i, 0x80FF));
#pragma unroll
        for (int k = 0; k < 8; ++k)
            accum(hv[k], p[k] ? ex[k] : 0.f);
    }

    // combine the 2 groups of each node: butterfly over lane 16
#pragma unroll
    for (int i = 0; i < 4; ++i) {
        acc2[i].x += __shfl_xor(acc2[i].x, 16);
        acc2[i].y += __shfl_xor(acc2[i].y, 16);
    }
    den += __shfl_xor(den, 16);
    if (g2 != 0) return;   // lanes hl<16 of each half write their node

    const float inv = 1.f / den;
    float4 b0 = *(const float4*)&bias[c0];
    float4 b1 = *(const float4*)&bias[c0 + 4];
    float v[8];
    v[0] = acc2[0].x * inv + b0.x; v[1] = acc2[0].y * inv + b0.y;
    v[2] = acc2[1].x * inv + b0.z; v[3] = acc2[1].y * inv + b0.w;
    v[4] = acc2[2].x * inv + b1.x; v[5] = acc2[2].y * inv + b1.y;
    v[6] = acc2[3].x * inv + b1.z; v[7] = acc2[3].y * inv + b1.w;
    if (FINAL) {
        float* op = (float*)out + (size_t)d * 128 + c0;
        *(float4*)op       = make_float4(v[0], v[1], v[2], v[3]);
        *(float4*)(op + 4) = make_float4(v[4], v[5], v[6], v[7]);
    } else {
#pragma unroll
        for (int i = 0; i < 8; ++i) v[i] = v[i] > 0.f ? v[i] : expm1f(v[i]);
        unsigned int pk[4];
#pragma unroll
        for (int i = 0; i < 4; ++i)
            pk[i] = (unsigned int)f2bf_u(v[2 * i]) | ((unsigned int)f2bf_u(v[2 * i + 1]) << 16);
        *(uint4*)((unsigned short*)out + (size_t)d * 128 + c0) =
            make_uint4(pk[0], pk[1], pk[2], pk[3]);
    }
}

// ---------------------------------------------------------------------------
extern "C" void kernel_launch(void* const* d_in, const int* in_sizes, int n_in,
                              void* d_out, int out_size, void* d_ws, size_t ws_size,
                              hipStream_t stream) {
    const float* x      = (const float*)d_in[0];
    const int*   ei     = (const int*)d_in[1];
    const float* W1     = (const float*)d_in[2];
    const float* a_src1 = (const float*)d_in[3];
    const float* a_dst1 = (const float*)d_in[4];
    const float* b1     = (const float*)d_in[5];
    const float* W2     = (const float*)d_in[6];
    const float* a_src2 = (const float*)d_in[7];
    const float* a_dst2 = (const float*)d_in[8];
    const float* b2     = (const float*)d_in[9];

    const int N = NN;

    // Workspace: explicit BYTE offsets, every buffer 16B-aligned.
    char* base = (char*)d_ws;
    int*   cnt  = (int*)(base + 0);                       //  50000 i
    int*   csrc = (int*)(base + 200000);                  //  50000*64 i (bucketed)
    float* als  = (float*)(base + 13000000);              // 200000 f
    float* ald  = (float*)(base + 13800000);              // 200000 f
    unsigned short* h   = (unsigned short*)(base + 14600000);  // N*128 bf16
    unsigned short* x2  = (unsigned short*)(base + 27400000);  // N*128 bf16
    unsigned short* wt1 = (unsigned short*)(base + 40200000);  // 16384 bf16
    unsigned short* wt2 = (unsigned short*)(base + 40232768);  // 16384 bf16
    // total ~40.27 MB

    const int gemmGrid  = (N + 63) / 64;          // 782
    const int edgeGrid  = (NE + 255) / 256;       // 2344
    const int zeroGrid  = (N + 255) / 256;        // 196
    const int aggGrid   = N / 8;                  // 6250 (2 nodes/wave, 4 waves/block)

    prep_zero<<<128 + zeroGrid, 256, 0, stream>>>(W1, W2, wt1, wt2, cnt);
    csr_fill<<<edgeGrid, 256, 0, stream>>>(ei, cnt, csrc);
    gemm_fused<4, 1><<<gemmGrid, 256, 0, stream>>>(x, wt1, a_src1, a_dst1, h, als, ald, N);
    aggregate<4, 0><<<aggGrid, 256, 0, stream>>>(cnt, csrc, h, als, ald, b1, x2);
    gemm_fused<1, 0><<<gemmGrid, 256, 0, stream>>>(x2, wt2, a_src2, a_dst2, h, als, ald, N);
    aggregate<1, 1><<<aggGrid, 256, 0, stream>>>(cnt, csrc, h, als, ald, b2, d_out);
}